// Round 8
// baseline (222.128 us; speedup 1.0000x reference)
//
#include <hip/hip_runtime.h>
#include <cstdint>

#define NTOT 73728      // B*H*W = 32*48*48
#define CTOT 512
#define MGRP 128        // members per group
#define EPSV 1e-7f
#define LDP  72         // LDS row stride in bf16 (144 B, 16B-aligned)

typedef float4 f4;
typedef __attribute__((ext_vector_type(8))) short bf16x8;   // 8 bf16 (4 VGPRs)
typedef __attribute__((ext_vector_type(4))) float f32x4;
typedef __attribute__((ext_vector_type(16))) float f32x16;

__device__ __forceinline__ f4 ld4(const float* p){ return *(const f4*)p; }

__device__ __forceinline__ ushort f2bf(float f){  // RNE fp32 -> bf16
    uint32_t u = __builtin_bit_cast(uint32_t, f);
    uint32_t r = (u + 0x7FFFu + ((u >> 16) & 1u)) >> 16;
    return (ushort)r;
}

// ---------------- K1: Sxx partials (MFMA) + Sx partials + xb (bf16 x) ----------------
// grid (nchunk, 4), block 512 (8 waves, 2x4; wave tile 64x32 of 128x128 output).
// K-tile = 64 samples, double-buffered LDS [channel][sample] bf16, stride LDP.
// Octet XOR-swizzle: sample-octet o of row ch lives at position o ^ ((ch>>3)&7).
__global__ __launch_bounds__(512) void k_cov(
    const float* __restrict__ x, float* __restrict__ sxxPart,
    float* __restrict__ sxPart, ushort* __restrict__ xb, int nchunk, int rowsPer)
{
    const int chunk = blockIdx.x, g = blockIdx.y;
    const int t = threadIdx.x;
    const int lane = t & 63, wid = t >> 6;
    const int wm = wid >> 2, wn = wid & 3;
    const int l15 = lane & 15, l4 = lane >> 4;

    __shared__ ushort xs[2][128 * LDP];   // 2 x 18,432 B
    __shared__ float sxbuf[512];

    const int c = t & 127;                // staging channel
    const int o = t >> 7;                 // octet id: handles octets o and o+4
    const int ckey = (c >> 3) & 7;        // swizzle key for staging row c
    const size_t rowbase = (size_t)chunk * rowsPer;
    const float* xp = x + rowbase * CTOT + (size_t)g * MGRP + c;

    // xb writer mapping: ws_ = sample-in-tile, co/co+8 = channel-octets (16 ch/thread)
    const int ws_ = t >> 3;               // 0..63 sample
    const int co  = t & 7;                // 0..7 -> octets co and co+8
    const int wv  = ws_ >> 3;             // logical octet of my sample (uniform per wave)
    ushort* xbp = xb + (rowbase + ws_) * CTOT + (size_t)g * MGRP + co * 8;

    f32x4 acc[4][2];
#pragma unroll
    for (int i = 0; i < 4; ++i)
#pragma unroll
        for (int j = 0; j < 2; ++j) acc[i][j] = (f32x4){0.f, 0.f, 0.f, 0.f};
    float sx = 0.f;

    float v[16];
#pragma unroll
    for (int e = 0; e < 8; ++e) {
        v[e]     = xp[(size_t)(o * 8 + e) * CTOT];
        v[8 + e] = xp[(size_t)((o + 4) * 8 + e) * CTOT];
    }

    const int niter = rowsPer / 64;
    int cur = 0;
    for (int it = 0; it < niter; ++it) {
        uint32_t pkA[4], pkB[4];
#pragma unroll
        for (int e = 0; e < 4; ++e) {
            sx += v[2*e] + v[2*e+1] + v[8+2*e] + v[8+2*e+1];
            pkA[e] = (uint32_t)f2bf(v[2*e])   | ((uint32_t)f2bf(v[2*e+1])   << 16);
            pkB[e] = (uint32_t)f2bf(v[8+2*e]) | ((uint32_t)f2bf(v[8+2*e+1]) << 16);
        }
        *(uint4*)&xs[cur][c * LDP + (o ^ ckey) * 8]       = make_uint4(pkA[0], pkA[1], pkA[2], pkA[3]);
        *(uint4*)&xs[cur][c * LDP + ((o + 4) ^ ckey) * 8] = make_uint4(pkB[0], pkB[1], pkB[2], pkB[3]);
        __syncthreads();                  // single barrier per iter (dbuf)
        if (it + 1 < niter) {
            const float* np = xp + (size_t)(it + 1) * 64 * CTOT;
#pragma unroll
            for (int e = 0; e < 8; ++e) {
                v[e]     = np[(size_t)(o * 8 + e) * CTOT];
                v[8 + e] = np[(size_t)((o + 4) * 8 + e) * CTOT];
            }
        }
#pragma unroll
        for (int kc = 0; kc < 2; ++kc) {
            bf16x8 af[4], bfr[2];
#pragma unroll
            for (int tm = 0; tm < 4; ++tm) {
                int ch = wm*64 + tm*16 + l15;
                af[tm] = *(const bf16x8*)&xs[cur][ch * LDP + (((kc*4 + l4) ^ ((ch>>3)&7)) * 8)];
            }
#pragma unroll
            for (int tn = 0; tn < 2; ++tn) {
                int ch = wn*32 + tn*16 + l15;
                bfr[tn] = *(const bf16x8*)&xs[cur][ch * LDP + (((kc*4 + l4) ^ ((ch>>3)&7)) * 8)];
            }
#pragma unroll
            for (int tm = 0; tm < 4; ++tm)
#pragma unroll
                for (int tn = 0; tn < 2; ++tn)
                    acc[tm][tn] = __builtin_amdgcn_mfma_f32_16x16x32_bf16(
                        af[tm], bfr[tn], acc[tm][tn], 0, 0, 0);
        }
        // emit xb tile: gather 16 channels of one sample (conflict-free via swizzle)
        {
            const int pos = ((wv ^ co) & 7) * 8 + (ws_ & 7);
            uint32_t pw[4], pw2[4];
#pragma unroll
            for (int e = 0; e < 4; ++e) {
                uint32_t lo  = xs[cur][(co*8 + 2*e)       * LDP + pos];
                uint32_t hi  = xs[cur][(co*8 + 2*e + 1)   * LDP + pos];
                pw[e]  = lo  | (hi  << 16);
                uint32_t lo2 = xs[cur][((co+8)*8 + 2*e)     * LDP + pos];
                uint32_t hi2 = xs[cur][((co+8)*8 + 2*e + 1) * LDP + pos];
                pw2[e] = lo2 | (hi2 << 16);
            }
            ushort* dst = xbp + (size_t)it * 64 * CTOT;
            *(uint4*)dst        = make_uint4(pw[0],  pw[1],  pw[2],  pw[3]);
            *(uint4*)(dst + 64) = make_uint4(pw2[0], pw2[1], pw2[2], pw2[3]);
        }
        cur ^= 1;
    }

    float* op = sxxPart + ((size_t)g * nchunk + chunk) * 16384;
#pragma unroll
    for (int tm = 0; tm < 4; ++tm)
#pragma unroll
        for (int tn = 0; tn < 2; ++tn)
#pragma unroll
            for (int r = 0; r < 4; ++r) {
                int i = wm*64 + tm*16 + l4*4 + r;
                int j = wn*32 + tn*16 + l15;
                op[i * 128 + j] = acc[tm][tn][r];
            }

    sxbuf[t] = sx;
    __syncthreads();
    if (t < 128) {
        float s = sxbuf[t] + sxbuf[t + 128] + sxbuf[t + 256] + sxbuf[t + 384];
        sxPart[((size_t)g * nchunk + chunk) * 128 + t] = s;
    }
}

// ---------------- K2: reduce Sxx partials over chunks ----------------
__global__ __launch_bounds__(256) void k_reduce(
    const float* __restrict__ sxxPart, float* __restrict__ gSxx, int nchunk)
{
    int g = blockIdx.y;
    int idx = blockIdx.x * 256 + threadIdx.x;
    float s = 0.f;
#pragma unroll 8
    for (int c = 0; c < nchunk; ++c)
        s += sxxPart[((size_t)g * nchunk + c) * 16384 + idx];
    gSxx[g * 16384 + idx] = s;
}

// ---------------- K3: finalize -> mean, trace, sigma, P1 ----------------
__global__ __launch_bounds__(256) void k_finalize(
    const float* __restrict__ gSxx, const float* __restrict__ sxPart,
    float* __restrict__ gSigma, float* __restrict__ gP,
    float* __restrict__ gMean, float* __restrict__ gScale, int nchunk)
{
    int g = blockIdx.x, t = threadIdx.x;
    __shared__ float mu[128];
    __shared__ float red[256];

    if (t < 128) {
        float s = 0.f;
        for (int c = 0; c < nchunk; ++c)
            s += sxPart[((size_t)g * nchunk + c) * 128 + t];
        float m = s / (float)NTOT;
        mu[t] = m;
        gMean[g * 128 + t] = m;
    }
    __syncthreads();

    float d = 0.f;
    if (t < 128) {
        float vdiag = gSxx[g * 16384 + t * 128 + t];
        float cv = (vdiag - (float)NTOT * mu[t] * mu[t]) / ((float)NTOT - 1.f);
        d = (1.f - EPSV) * cv + EPSV;
    }
    red[t] = d;
    __syncthreads();
    for (int s = 128; s > 0; s >>= 1) {
        if (t < s) red[t] += red[t + s];
        __syncthreads();
    }
    float tr = red[0];
    float invTr = 1.f / tr;
    if (t == 0) gScale[g] = rsqrtf(tr);

    for (int e = t; e < 16384; e += 256) {
        int i = e >> 7, j = e & 127;
        float cv = (gSxx[g * 16384 + e] - (float)NTOT * mu[i] * mu[j]) / ((float)NTOT - 1.f);
        float ce = (1.f - EPSV) * cv + ((i == j) ? EPSV : 0.f);
        float sg = ce * invTr;
        gSigma[g * 16384 + e] = sg;
        gP[g * 16384 + e] = ((i == j) ? 1.5f : 0.f) - 0.5f * sg;
    }
}

// ---------------- K4: P2 = P@P, PS = P@Sigma ----------------
__global__ __launch_bounds__(256) void k_ns1(
    const float* __restrict__ gP, const float* __restrict__ gS,
    float* __restrict__ gP2, float* __restrict__ gPS)
{
    int g = blockIdx.y;
    int row = blockIdx.x * 8 + (threadIdx.x >> 5);
    int cq = (threadIdx.x & 31) * 4;
    const float* P = gP + g * 16384;
    const float* S = gS + g * 16384;
    f4 a1 = {0.f,0.f,0.f,0.f}, a2 = {0.f,0.f,0.f,0.f};
    for (int k = 0; k < 128; k += 4) {
        f4 a = ld4(&P[row * 128 + k]);
        float av[4] = {a.x, a.y, a.z, a.w};
#pragma unroll
        for (int kk = 0; kk < 4; ++kk) {
            f4 b1 = ld4(&P[(k + kk) * 128 + cq]);
            f4 b2 = ld4(&S[(k + kk) * 128 + cq]);
            float aa = av[kk];
            a1.x += aa * b1.x; a1.y += aa * b1.y; a1.z += aa * b1.z; a1.w += aa * b1.w;
            a2.x += aa * b2.x; a2.y += aa * b2.y; a2.z += aa * b2.z; a2.w += aa * b2.w;
        }
    }
    *(f4*)&gP2[g * 16384 + row * 128 + cq] = a1;
    *(f4*)&gPS[g * 16384 + row * 128 + cq] = a2;
}

// ---------------- K5: P = 1.5P - 0.5*(P2@PS); final iter also emits bf16 W ----------------
__global__ __launch_bounds__(256) void k_ns2(
    float* __restrict__ gP, const float* __restrict__ gP2, const float* __restrict__ gPS,
    const float* __restrict__ gScale, ushort* __restrict__ gWb, int writeW)
{
    int g = blockIdx.y;
    int row = blockIdx.x * 8 + (threadIdx.x >> 5);
    int cq = (threadIdx.x & 31) * 4;
    const float* A = gP2 + g * 16384;
    const float* B = gPS + g * 16384;
    f4 acc = {0.f,0.f,0.f,0.f};
    for (int k = 0; k < 128; k += 4) {
        f4 a = ld4(&A[row * 128 + k]);
        float av[4] = {a.x, a.y, a.z, a.w};
#pragma unroll
        for (int kk = 0; kk < 4; ++kk) {
            f4 b = ld4(&B[(k + kk) * 128 + cq]);
            float aa = av[kk];
            acc.x += aa * b.x; acc.y += aa * b.y; acc.z += aa * b.z; acc.w += aa * b.w;
        }
    }
    size_t off = (size_t)g * 16384 + row * 128 + cq;
    f4 p = ld4(&gP[off]);
    f4 r;
    r.x = 1.5f * p.x - 0.5f * acc.x;
    r.y = 1.5f * p.y - 0.5f * acc.y;
    r.z = 1.5f * p.z - 0.5f * acc.z;
    r.w = 1.5f * p.w - 0.5f * acc.w;
    *(f4*)&gP[off] = r;
    if (writeW) {
        float sc = gScale[g];
        uint32_t lo = (uint32_t)f2bf(r.x * sc) | ((uint32_t)f2bf(r.y * sc) << 16);
        uint32_t hi = (uint32_t)f2bf(r.z * sc) | ((uint32_t)f2bf(r.w * sc) << 16);
        *(uint2*)&gWb[off] = make_uint2(lo, hi);
    }
}

// ---------------- K6: beta' = beta - gamma*(W@mu) ----------------
__global__ __launch_bounds__(128) void k_bprime(
    const float* __restrict__ gP, const float* __restrict__ gMean,
    const float* __restrict__ gScale, const float* __restrict__ gamma,
    const float* __restrict__ beta, float* __restrict__ gBp)
{
    int g = blockIdx.x, j = threadIdx.x;
    float s = 0.f;
    for (int k = 0; k < 128; ++k)
        s += gMean[g * 128 + k] * gP[g * 16384 + k * 128 + j];
    s *= gScale[g];
    int c = g * 128 + j;
    gBp[c] = beta[c] - gamma[c] * s;
}

// ---------------- K7: out = gamma*(xb @ Wb) + beta'  (32x32x16 MFMA, LDS epilogue) ----------------
// grid (NTOT/128, 4), block 256 (4 waves; each wave 32 samples x 128 cols).
__global__ __launch_bounds__(256) void k_apply(
    const ushort* __restrict__ xb, const ushort* __restrict__ gWb,
    const float* __restrict__ gamma, const float* __restrict__ gBp,
    float* __restrict__ out)
{
    const int g = blockIdx.y;
    const int t = threadIdx.x, lane = t & 63, w = t >> 6;
    const int l31 = lane & 31, hi = lane >> 5;
    const int s0 = blockIdx.x * 128 + w * 32;

    __shared__ float ep[4][32 * 36];      // per-wave staging, stride 36 dw (144 B)
    float* my = ep[w];

    // A fragments: 32 samples x K=128, loaded once (8 x b128)
    const ushort* ap = xb + (size_t)(s0 + l31) * CTOT + g * MGRP + hi * 8;
    bf16x8 af[8];
#pragma unroll
    for (int ks = 0; ks < 8; ++ks)
        af[ks] = *(const bf16x8*)(ap + ks * 16);

    const ushort* Wg = gWb + g * 16384;

#pragma unroll
    for (int ct = 0; ct < 4; ++ct) {
        bf16x8 wf[8];
#pragma unroll
        for (int ks = 0; ks < 8; ++ks)   // W symmetric: row (ct*32+l31), k contiguous
            wf[ks] = *(const bf16x8*)&Wg[(ct*32 + l31) * 128 + ks*16 + hi*8];
        int ch = g * MGRP + ct*32 + l31;
        float gm = gamma[ch], bp = gBp[ch];
        f32x16 acc = {};
#pragma unroll
        for (int ks = 0; ks < 8; ++ks)
            acc = __builtin_amdgcn_mfma_f32_32x32x16_bf16(af[ks], wf[ks], acc, 0, 0, 0);
        // stage tile in LDS (wave-synchronous; C layout: col=l31, row=(r&3)+8*(r>>2)+4*hi)
#pragma unroll
        for (int r = 0; r < 16; ++r) {
            int row = (r & 3) + 8 * (r >> 2) + 4 * hi;
            my[row * 36 + l31] = gm * acc[r] + bp;
        }
        // coalesced read-back + 128B nt stores
        int rr = lane >> 3, c4 = (lane & 7) * 4;
#pragma unroll
        for (int p = 0; p < 4; ++p) {
            int row = p * 8 + rr;
            f32x4 v = *(const f32x4*)&my[row * 36 + c4];
            __builtin_nontemporal_store(v,
                (f32x4*)&out[(size_t)(s0 + row) * CTOT + g * MGRP + ct*32 + c4]);
        }
    }
}

// ---------------- launch ----------------
extern "C" void kernel_launch(void* const* d_in, const int* in_sizes, int n_in,
                              void* d_out, int out_size, void* d_ws, size_t ws_size,
                              hipStream_t stream)
{
    const float* x     = (const float*)d_in[0];
    const float* gamma = (const float*)d_in[1];
    const float* beta  = (const float*)d_in[2];
    float* out = (float*)d_out;
    float* ws  = (float*)d_ws;

    int nchunk = 192;   // rowsPer = 384 (divisible by 64); 768 blocks = 3/CU
    auto need = [](int nc) -> size_t {
        return ((size_t)nc * 4 * 16384 + (size_t)nc * 4 * 128 +
                5ull * 4 * 16384 + 512 + 16 + 512 + 32768 +
                (size_t)NTOT * CTOT / 2) * 4;
    };
    while (nchunk > 12 && need(nchunk) > ws_size) nchunk >>= 1;
    int rowsPer = NTOT / nchunk;

    size_t off = 0;
    float* sxxPart = ws + off; off += (size_t)nchunk * 4 * 16384;
    float* sxPart  = ws + off; off += (size_t)nchunk * 4 * 128;
    float* gSxx    = ws + off; off += 4 * 16384;
    float* gSigma  = ws + off; off += 4 * 16384;
    float* gP      = ws + off; off += 4 * 16384;
    float* gP2     = ws + off; off += 4 * 16384;
    float* gPS     = ws + off; off += 4 * 16384;
    float* gMean   = ws + off; off += 512;
    float* gScale  = ws + off; off += 16;
    float* gBp     = ws + off; off += 512;
    ushort* gWb    = (ushort*)(ws + off); off += 32768;   // 4*16384 bf16 = 32768 float-slots
    ushort* xb     = (ushort*)(ws + off); off += (size_t)NTOT * CTOT / 2;

    k_cov<<<dim3(nchunk, 4), 512, 0, stream>>>(x, sxxPart, sxPart, xb, nchunk, rowsPer);
    k_reduce<<<dim3(64, 4), 256, 0, stream>>>(sxxPart, gSxx, nchunk);
    k_finalize<<<4, 256, 0, stream>>>(gSxx, sxPart, gSigma, gP, gMean, gScale, nchunk);
    k_ns1<<<dim3(16, 4), 256, 0, stream>>>(gP, gSigma, gP2, gPS);
    k_ns2<<<dim3(16, 4), 256, 0, stream>>>(gP, gP2, gPS, gScale, gWb, 0);
    k_ns1<<<dim3(16, 4), 256, 0, stream>>>(gP, gSigma, gP2, gPS);
    k_ns2<<<dim3(16, 4), 256, 0, stream>>>(gP, gP2, gPS, gScale, gWb, 1);
    k_bprime<<<4, 128, 0, stream>>>(gP, gMean, gScale, gamma, beta, gBp);
    k_apply<<<dim3(NTOT / 128, 4), 256, 0, stream>>>(xb, gWb, gamma, gBp, out);
}

// Round 9
// 204.804 us; speedup vs baseline: 1.0846x; 1.0846x over previous
//
#include <hip/hip_runtime.h>
#include <cstdint>

#define NTOT 73728      // B*H*W = 32*48*48
#define CTOT 512
#define MGRP 128        // members per group
#define EPSV 1e-7f

typedef float4 f4;
typedef __attribute__((ext_vector_type(8))) short bf16x8;   // 8 bf16 (4 VGPRs)
typedef __attribute__((ext_vector_type(4))) float f32x4;
typedef __attribute__((ext_vector_type(16))) float f32x16;

__device__ __forceinline__ f4 ld4(const float* p){ return *(const f4*)p; }

__device__ __forceinline__ ushort f2bf(float f){  // RNE fp32 -> bf16
    uint32_t u = __builtin_bit_cast(uint32_t, f);
    uint32_t r = (u + 0x7FFFu + ((u >> 16) & 1u)) >> 16;
    return (ushort)r;
}

__device__ __forceinline__ bf16x8 pack8(const float v[8]) {
    union { bf16x8 b; uint32_t u[4]; } r;
#pragma unroll
    for (int i = 0; i < 4; ++i)
        r.u[i] = (uint32_t)f2bf(v[2*i]) | ((uint32_t)f2bf(v[2*i+1]) << 16);
    return r.b;
}

// ---------------- K1: Sxx partials, LDS-free / barrier-free ----------------
// grid (nchunk, 4), block 256 (4 waves, 2x2; each wave a 64x64 tile of 128x128).
// Fragments built directly from global: lane l31 = channel, hi*8+e = sample.
// Diagonal waves (wr==wc) reuse row frags as col frags. No barriers in K-loop.
__global__ __launch_bounds__(256) void k_cov(
    const float* __restrict__ x, float* __restrict__ sxxPart,
    float* __restrict__ sxPart, int nchunk, int rowsPer)
{
    const int chunk = blockIdx.x, g = blockIdx.y;
    const int t = threadIdx.x;
    const int lane = t & 63, wid = t >> 6;
    const int wr = wid >> 1, wc = wid & 1;       // 2x2 wave grid
    const int l31 = lane & 31, hi = lane >> 5;
    const size_t rowbase = (size_t)chunk * rowsPer;

    __shared__ float sxred[256];

    const float* xg = x + (size_t)g * MGRP;

    f32x16 acc[2][2];
#pragma unroll
    for (int a = 0; a < 2; ++a)
#pragma unroll
        for (int b = 0; b < 2; ++b) acc[a][b] = (f32x16){};
    float sxa0 = 0.f, sxa1 = 0.f;

    for (int kb = 0; kb < rowsPer; kb += 16) {
        const float* pk = xg + (rowbase + kb + (size_t)hi * 8) * CTOT;
        bf16x8 fr[2], fc[2];
        // row frags (channels wr*64 + a*32 + l31)
        {
            const float* p0 = pk + wr*64 + l31;
            float v[8];
#pragma unroll
            for (int e = 0; e < 8; ++e) v[e] = p0[(size_t)e * CTOT];
#pragma unroll
            for (int e = 0; e < 8; ++e) sxa0 += v[e];
            fr[0] = pack8(v);
            const float* p1 = pk + wr*64 + 32 + l31;
            float w[8];
#pragma unroll
            for (int e = 0; e < 8; ++e) w[e] = p1[(size_t)e * CTOT];
#pragma unroll
            for (int e = 0; e < 8; ++e) sxa1 += w[e];
            fr[1] = pack8(w);
        }
        if (wr != wc) {   // wave-uniform branch
#pragma unroll
            for (int b = 0; b < 2; ++b) {
                const float* p = pk + wc*64 + b*32 + l31;
                float v[8];
#pragma unroll
                for (int e = 0; e < 8; ++e) v[e] = p[(size_t)e * CTOT];
                fc[b] = pack8(v);
            }
        } else {
            fc[0] = fr[0]; fc[1] = fr[1];
        }
#pragma unroll
        for (int a = 0; a < 2; ++a)
#pragma unroll
            for (int b = 0; b < 2; ++b)
                acc[a][b] = __builtin_amdgcn_mfma_f32_32x32x16_bf16(
                    fr[a], fc[b], acc[a][b], 0, 0, 0);
    }

    float* op = sxxPart + ((size_t)g * nchunk + chunk) * 16384;
#pragma unroll
    for (int a = 0; a < 2; ++a)
#pragma unroll
        for (int b = 0; b < 2; ++b)
#pragma unroll
            for (int r = 0; r < 16; ++r) {
                int i = wr*64 + a*32 + (r & 3) + 8 * (r >> 2) + 4 * hi;
                int j = wc*64 + b*32 + l31;
                op[i * 128 + j] = acc[a][b][r];
            }

    // column sums: wc==0 waves' row frags tile all 128 channels exactly once
    if (wc == 0) {
        sxred[(wr*64 + l31) * 2 + hi]      = sxa0;
        sxred[(wr*64 + 32 + l31) * 2 + hi] = sxa1;
    }
    __syncthreads();
    if (t < 128)
        sxPart[((size_t)g * nchunk + chunk) * 128 + t] = sxred[t*2] + sxred[t*2 + 1];
}

// ---------------- K2: reduce Sxx partials over chunks ----------------
__global__ __launch_bounds__(256) void k_reduce(
    const float* __restrict__ sxxPart, float* __restrict__ gSxx, int nchunk)
{
    int g = blockIdx.y;
    int idx = blockIdx.x * 256 + threadIdx.x;
    float s = 0.f;
#pragma unroll 8
    for (int c = 0; c < nchunk; ++c)
        s += sxxPart[((size_t)g * nchunk + c) * 16384 + idx];
    gSxx[g * 16384 + idx] = s;
}

// ---------------- K3: finalize -> mean, trace, sigma, P1 ----------------
__global__ __launch_bounds__(256) void k_finalize(
    const float* __restrict__ gSxx, const float* __restrict__ sxPart,
    float* __restrict__ gSigma, float* __restrict__ gP,
    float* __restrict__ gMean, float* __restrict__ gScale, int nchunk)
{
    int g = blockIdx.x, t = threadIdx.x;
    __shared__ float mu[128];
    __shared__ float red[256];

    if (t < 128) {
        float s = 0.f;
        for (int c = 0; c < nchunk; ++c)
            s += sxPart[((size_t)g * nchunk + c) * 128 + t];
        float m = s / (float)NTOT;
        mu[t] = m;
        gMean[g * 128 + t] = m;
    }
    __syncthreads();

    float d = 0.f;
    if (t < 128) {
        float vdiag = gSxx[g * 16384 + t * 128 + t];
        float cv = (vdiag - (float)NTOT * mu[t] * mu[t]) / ((float)NTOT - 1.f);
        d = (1.f - EPSV) * cv + EPSV;
    }
    red[t] = d;
    __syncthreads();
    for (int s = 128; s > 0; s >>= 1) {
        if (t < s) red[t] += red[t + s];
        __syncthreads();
    }
    float tr = red[0];
    float invTr = 1.f / tr;
    if (t == 0) gScale[g] = rsqrtf(tr);

    for (int e = t; e < 16384; e += 256) {
        int i = e >> 7, j = e & 127;
        float cv = (gSxx[g * 16384 + e] - (float)NTOT * mu[i] * mu[j]) / ((float)NTOT - 1.f);
        float ce = (1.f - EPSV) * cv + ((i == j) ? EPSV : 0.f);
        float sg = ce * invTr;
        gSigma[g * 16384 + e] = sg;
        gP[g * 16384 + e] = ((i == j) ? 1.5f : 0.f) - 0.5f * sg;
    }
}

// ---------------- K4: P2 = P@P, PS = P@Sigma ----------------
__global__ __launch_bounds__(256) void k_ns1(
    const float* __restrict__ gP, const float* __restrict__ gS,
    float* __restrict__ gP2, float* __restrict__ gPS)
{
    int g = blockIdx.y;
    int row = blockIdx.x * 8 + (threadIdx.x >> 5);
    int cq = (threadIdx.x & 31) * 4;
    const float* P = gP + g * 16384;
    const float* S = gS + g * 16384;
    f4 a1 = {0.f,0.f,0.f,0.f}, a2 = {0.f,0.f,0.f,0.f};
    for (int k = 0; k < 128; k += 4) {
        f4 a = ld4(&P[row * 128 + k]);
        float av[4] = {a.x, a.y, a.z, a.w};
#pragma unroll
        for (int kk = 0; kk < 4; ++kk) {
            f4 b1 = ld4(&P[(k + kk) * 128 + cq]);
            f4 b2 = ld4(&S[(k + kk) * 128 + cq]);
            float aa = av[kk];
            a1.x += aa * b1.x; a1.y += aa * b1.y; a1.z += aa * b1.z; a1.w += aa * b1.w;
            a2.x += aa * b2.x; a2.y += aa * b2.y; a2.z += aa * b2.z; a2.w += aa * b2.w;
        }
    }
    *(f4*)&gP2[g * 16384 + row * 128 + cq] = a1;
    *(f4*)&gPS[g * 16384 + row * 128 + cq] = a2;
}

// ---------------- K5: P = 1.5P - 0.5*(P2@PS); final iter also emits bf16 W ----------------
__global__ __launch_bounds__(256) void k_ns2(
    float* __restrict__ gP, const float* __restrict__ gP2, const float* __restrict__ gPS,
    const float* __restrict__ gScale, ushort* __restrict__ gWb, int writeW)
{
    int g = blockIdx.y;
    int row = blockIdx.x * 8 + (threadIdx.x >> 5);
    int cq = (threadIdx.x & 31) * 4;
    const float* A = gP2 + g * 16384;
    const float* B = gPS + g * 16384;
    f4 acc = {0.f,0.f,0.f,0.f};
    for (int k = 0; k < 128; k += 4) {
        f4 a = ld4(&A[row * 128 + k]);
        float av[4] = {a.x, a.y, a.z, a.w};
#pragma unroll
        for (int kk = 0; kk < 4; ++kk) {
            f4 b = ld4(&B[(k + kk) * 128 + cq]);
            float aa = av[kk];
            acc.x += aa * b.x; acc.y += aa * b.y; acc.z += aa * b.z; acc.w += aa * b.w;
        }
    }
    size_t off = (size_t)g * 16384 + row * 128 + cq;
    f4 p = ld4(&gP[off]);
    f4 r;
    r.x = 1.5f * p.x - 0.5f * acc.x;
    r.y = 1.5f * p.y - 0.5f * acc.y;
    r.z = 1.5f * p.z - 0.5f * acc.z;
    r.w = 1.5f * p.w - 0.5f * acc.w;
    *(f4*)&gP[off] = r;
    if (writeW) {
        float sc = gScale[g];
        uint32_t lo = (uint32_t)f2bf(r.x * sc) | ((uint32_t)f2bf(r.y * sc) << 16);
        uint32_t hi = (uint32_t)f2bf(r.z * sc) | ((uint32_t)f2bf(r.w * sc) << 16);
        *(uint2*)&gWb[off] = make_uint2(lo, hi);
    }
}

// ---------------- K6: beta' = beta - gamma*(W@mu) ----------------
__global__ __launch_bounds__(128) void k_bprime(
    const float* __restrict__ gP, const float* __restrict__ gMean,
    const float* __restrict__ gScale, const float* __restrict__ gamma,
    const float* __restrict__ beta, float* __restrict__ gBp)
{
    int g = blockIdx.x, j = threadIdx.x;
    float s = 0.f;
    for (int k = 0; k < 128; ++k)
        s += gMean[g * 128 + k] * gP[g * 16384 + k * 128 + j];
    s *= gScale[g];
    int c = g * 128 + j;
    gBp[c] = beta[c] - gamma[c] * s;
}

// ---------------- K7: out = gamma*(bf16(X)@Wb) + beta'  (32x32x16 MFMA) ----------------
// grid (NTOT/128, 4), block 256 (4 waves; each wave 32 samples x 128 cols).
__global__ __launch_bounds__(256) void k_apply(
    const float* __restrict__ x, const ushort* __restrict__ gWb,
    const float* __restrict__ gamma, const float* __restrict__ gBp,
    float* __restrict__ out)
{
    const int g = blockIdx.y;
    const int t = threadIdx.x, lane = t & 63, w = t >> 6;
    const int l31 = lane & 31, hi = lane >> 5;
    const int s0 = blockIdx.x * 128 + w * 32;

    // ---- issue all A loads up front (16 x dwordx4 in flight) ----
    const float* ap = x + (size_t)(s0 + l31) * CTOT + g * MGRP + hi * 8;
    f4 a0[8], a1[8];
#pragma unroll
    for (int ks = 0; ks < 8; ++ks) {
        a0[ks] = ld4(ap + ks * 16);
        a1[ks] = ld4(ap + ks * 16 + 4);
    }

    float gm[4], bp[4];
#pragma unroll
    for (int ct = 0; ct < 4; ++ct) {
        int ch = g * MGRP + ct * 32 + l31;
        gm[ct] = gamma[ch];
        bp[ct] = gBp[ch];
    }

    bf16x8 af[8];
#pragma unroll
    for (int ks = 0; ks < 8; ++ks) {
        union { bf16x8 v; ushort u[8]; } cv;
        cv.u[0] = f2bf(a0[ks].x); cv.u[1] = f2bf(a0[ks].y);
        cv.u[2] = f2bf(a0[ks].z); cv.u[3] = f2bf(a0[ks].w);
        cv.u[4] = f2bf(a1[ks].x); cv.u[5] = f2bf(a1[ks].y);
        cv.u[6] = f2bf(a1[ks].z); cv.u[7] = f2bf(a1[ks].w);
        af[ks] = cv.v;
    }

    const ushort* Wg = gWb + g * 16384;
#pragma unroll
    for (int ct = 0; ct < 4; ++ct) {
        bf16x8 wf[8];
#pragma unroll
        for (int ks = 0; ks < 8; ++ks)   // W symmetric: row (ct*32+l31), k contiguous
            wf[ks] = *(const bf16x8*)&Wg[(ct*32 + l31) * 128 + ks*16 + hi*8];
        f32x16 acc = {};
#pragma unroll
        for (int ks = 0; ks < 8; ++ks)
            acc = __builtin_amdgcn_mfma_f32_32x32x16_bf16(af[ks], wf[ks], acc, 0, 0, 0);
#pragma unroll
        for (int r = 0; r < 16; ++r) {
            int row = s0 + (r & 3) + 8 * (r >> 2) + 4 * hi;
            float val = gm[ct] * acc[r] + bp[ct];
            __builtin_nontemporal_store(val, &out[(size_t)row * CTOT + g * MGRP + ct * 32 + l31]);
        }
    }
}

// ---------------- launch ----------------
extern "C" void kernel_launch(void* const* d_in, const int* in_sizes, int n_in,
                              void* d_out, int out_size, void* d_ws, size_t ws_size,
                              hipStream_t stream)
{
    const float* x     = (const float*)d_in[0];
    const float* gamma = (const float*)d_in[1];
    const float* beta  = (const float*)d_in[2];
    float* out = (float*)d_out;
    float* ws  = (float*)d_ws;

    int nchunk = 128;   // rowsPer = 576 (divisible by 16)
    auto need = [](int nc) -> size_t {
        return ((size_t)nc * 4 * 16384 + (size_t)nc * 4 * 128 +
                5ull * 4 * 16384 + 512 + 16 + 512 + 32768) * 4;
    };
    while (nchunk > 16 && need(nchunk) > ws_size) nchunk >>= 1;
    int rowsPer = NTOT / nchunk;

    size_t off = 0;
    float* sxxPart = ws + off; off += (size_t)nchunk * 4 * 16384;
    float* sxPart  = ws + off; off += (size_t)nchunk * 4 * 128;
    float* gSxx    = ws + off; off += 4 * 16384;
    float* gSigma  = ws + off; off += 4 * 16384;
    float* gP      = ws + off; off += 4 * 16384;
    float* gP2     = ws + off; off += 4 * 16384;
    float* gPS     = ws + off; off += 4 * 16384;
    float* gMean   = ws + off; off += 512;
    float* gScale  = ws + off; off += 16;
    float* gBp     = ws + off; off += 512;
    ushort* gWb    = (ushort*)(ws + off); off += 32768;   // 4*16384 bf16 = 32768 float-slots

    k_cov<<<dim3(nchunk, 4), 256, 0, stream>>>(x, sxxPart, sxPart, nchunk, rowsPer);
    k_reduce<<<dim3(64, 4), 256, 0, stream>>>(sxxPart, gSxx, nchunk);
    k_finalize<<<4, 256, 0, stream>>>(gSxx, sxPart, gSigma, gP, gMean, gScale, nchunk);
    k_ns1<<<dim3(16, 4), 256, 0, stream>>>(gP, gSigma, gP2, gPS);
    k_ns2<<<dim3(16, 4), 256, 0, stream>>>(gP, gP2, gPS, gScale, gWb, 0);
    k_ns1<<<dim3(16, 4), 256, 0, stream>>>(gP, gSigma, gP2, gPS);
    k_ns2<<<dim3(16, 4), 256, 0, stream>>>(gP, gP2, gPS, gScale, gWb, 1);
    k_bprime<<<4, 128, 0, stream>>>(gP, gMean, gScale, gamma, beta, gBp);
    k_apply<<<dim3(NTOT / 128, 4), 256, 0, stream>>>(x, gWb, gamma, gBp, out);
}

// Round 12
// 197.324 us; speedup vs baseline: 1.1257x; 1.0379x over previous
//
#include <hip/hip_runtime.h>
#include <hip/hip_bf16.h>
#include <cstdint>

#define NTOT 73728      // B*H*W = 32*48*48
#define CTOT 512
#define MGRP 128        // members per group
#define EPSV 1e-7f

typedef float4 f4;
typedef __attribute__((ext_vector_type(8))) short bf16x8;   // 8 bf16 (4 VGPRs)
typedef __attribute__((ext_vector_type(4))) float f32x4;
typedef __attribute__((ext_vector_type(16))) float f32x16;

__device__ __forceinline__ f4 ld4(const float* p){ return *(const f4*)p; }

__device__ __forceinline__ ushort f2bf(float f){  // RNE fp32 -> bf16 (cold paths)
    uint32_t u = __builtin_bit_cast(uint32_t, f);
    uint32_t r = (u + 0x7FFFu + ((u >> 16) & 1u)) >> 16;
    return (ushort)r;
}

__device__ __forceinline__ uint32_t pk2(float a, float b){   // HW v_cvt_pk_bf16_f32
    __hip_bfloat162 h = __float22bfloat162_rn(make_float2(a, b));
    uint32_t u; __builtin_memcpy(&u, &h, 4);
    return u;
}

__device__ __forceinline__ bf16x8 pack8(const float v[8]) {
    union { bf16x8 b; uint32_t u[4]; } r;
#pragma unroll
    for (int i = 0; i < 4; ++i) r.u[i] = pk2(v[2*i], v[2*i+1]);
    return r.b;
}

// ---------------- K1: Sxx partials, LDS-free / barrier-free ----------------
// grid (nchunk, 4), block 256 (4 waves, 2x2; each wave a 64x64 tile of 128x128).
// Fragments built directly from global; native cvt_pk for fp32->bf16.
__global__ __launch_bounds__(256) void k_cov(
    const float* __restrict__ x, float* __restrict__ sxxPart,
    float* __restrict__ sxPart, int nchunk, int rowsPer)
{
    const int chunk = blockIdx.x, g = blockIdx.y;
    const int t = threadIdx.x;
    const int lane = t & 63, wid = t >> 6;
    const int wr = wid >> 1, wc = wid & 1;       // 2x2 wave grid
    const int l31 = lane & 31, hi = lane >> 5;
    const size_t rowbase = (size_t)chunk * rowsPer;

    __shared__ float sxred[256];

    const float* xg = x + (size_t)g * MGRP;

    f32x16 acc[2][2];
#pragma unroll
    for (int a = 0; a < 2; ++a)
#pragma unroll
        for (int b = 0; b < 2; ++b) acc[a][b] = (f32x16){};
    float sxa0 = 0.f, sxa1 = 0.f;

    for (int kb = 0; kb < rowsPer; kb += 16) {
        const float* pk = xg + (rowbase + kb + (size_t)hi * 8) * CTOT;
        bf16x8 fr[2], fc[2];
        {
            const float* p0 = pk + wr*64 + l31;
            float v[8];
#pragma unroll
            for (int e = 0; e < 8; ++e) v[e] = p0[(size_t)e * CTOT];
            const float* p1 = pk + wr*64 + 32 + l31;
            float w[8];
#pragma unroll
            for (int e = 0; e < 8; ++e) w[e] = p1[(size_t)e * CTOT];
            if (wc == 0) {   // only these waves' sums are consumed
#pragma unroll
                for (int e = 0; e < 8; ++e) { sxa0 += v[e]; sxa1 += w[e]; }
            }
            fr[0] = pack8(v);
            fr[1] = pack8(w);
        }
        if (wr != wc) {   // wave-uniform branch
#pragma unroll
            for (int b = 0; b < 2; ++b) {
                const float* p = pk + wc*64 + b*32 + l31;
                float v[8];
#pragma unroll
                for (int e = 0; e < 8; ++e) v[e] = p[(size_t)e * CTOT];
                fc[b] = pack8(v);
            }
        } else {
            fc[0] = fr[0]; fc[1] = fr[1];
        }
#pragma unroll
        for (int a = 0; a < 2; ++a)
#pragma unroll
            for (int b = 0; b < 2; ++b)
                acc[a][b] = __builtin_amdgcn_mfma_f32_32x32x16_bf16(
                    fr[a], fc[b], acc[a][b], 0, 0, 0);
    }

    float* op = sxxPart + ((size_t)g * nchunk + chunk) * 16384;
#pragma unroll
    for (int a = 0; a < 2; ++a)
#pragma unroll
        for (int b = 0; b < 2; ++b)
#pragma unroll
            for (int r = 0; r < 16; ++r) {
                int i = wr*64 + a*32 + (r & 3) + 8 * (r >> 2) + 4 * hi;
                int j = wc*64 + b*32 + l31;
                op[i * 128 + j] = acc[a][b][r];
            }

    if (wc == 0) {
        sxred[(wr*64 + l31) * 2 + hi]      = sxa0;
        sxred[(wr*64 + 32 + l31) * 2 + hi] = sxa1;
    }
    __syncthreads();
    if (t < 128)
        sxPart[((size_t)g * nchunk + chunk) * 128 + t] = sxred[t*2] + sxred[t*2 + 1];
}

// ---------------- K2: reduce Sxx partials over chunks ----------------
__global__ __launch_bounds__(256) void k_reduce(
    const float* __restrict__ sxxPart, float* __restrict__ gSxx, int nchunk)
{
    int g = blockIdx.y;
    int idx = blockIdx.x * 256 + threadIdx.x;
    float s = 0.f;
#pragma unroll 8
    for (int c = 0; c < nchunk; ++c)
        s += sxxPart[((size_t)g * nchunk + c) * 16384 + idx];
    gSxx[g * 16384 + idx] = s;
}

// ---------------- K3: finalize -> mean, trace, sigma, P1 ----------------
__global__ __launch_bounds__(256) void k_finalize(
    const float* __restrict__ gSxx, const float* __restrict__ sxPart,
    float* __restrict__ gSigma, float* __restrict__ gP,
    float* __restrict__ gMean, float* __restrict__ gScale, int nchunk)
{
    int g = blockIdx.x, t = threadIdx.x;
    __shared__ float mu[128];
    __shared__ float red[256];

    if (t < 128) {
        float s = 0.f;
        for (int c = 0; c < nchunk; ++c)
            s += sxPart[((size_t)g * nchunk + c) * 128 + t];
        float m = s / (float)NTOT;
        mu[t] = m;
        gMean[g * 128 + t] = m;
    }
    __syncthreads();

    float d = 0.f;
    if (t < 128) {
        float vdiag = gSxx[g * 16384 + t * 128 + t];
        float cv = (vdiag - (float)NTOT * mu[t] * mu[t]) / ((float)NTOT - 1.f);
        d = (1.f - EPSV) * cv + EPSV;
    }
    red[t] = d;
    __syncthreads();
    for (int s = 128; s > 0; s >>= 1) {
        if (t < s) red[t] += red[t + s];
        __syncthreads();
    }
    float tr = red[0];
    float invTr = 1.f / tr;
    if (t == 0) gScale[g] = rsqrtf(tr);

    for (int e = t; e < 16384; e += 256) {
        int i = e >> 7, j = e & 127;
        float cv = (gSxx[g * 16384 + e] - (float)NTOT * mu[i] * mu[j]) / ((float)NTOT - 1.f);
        float ce = (1.f - EPSV) * cv + ((i == j) ? EPSV : 0.f);
        float sg = ce * invTr;
        gSigma[g * 16384 + e] = sg;
        gP[g * 16384 + e] = ((i == j) ? 1.5f : 0.f) - 0.5f * sg;
    }
}

// ---------------- K4: P2 = P@P, PS = P@Sigma ----------------
__global__ __launch_bounds__(256) void k_ns1(
    const float* __restrict__ gP, const float* __restrict__ gS,
    float* __restrict__ gP2, float* __restrict__ gPS)
{
    int g = blockIdx.y;
    int row = blockIdx.x * 8 + (threadIdx.x >> 5);
    int cq = (threadIdx.x & 31) * 4;
    const float* P = gP + g * 16384;
    const float* S = gS + g * 16384;
    f4 a1 = {0.f,0.f,0.f,0.f}, a2 = {0.f,0.f,0.f,0.f};
    for (int k = 0; k < 128; k += 4) {
        f4 a = ld4(&P[row * 128 + k]);
        float av[4] = {a.x, a.y, a.z, a.w};
#pragma unroll
        for (int kk = 0; kk < 4; ++kk) {
            f4 b1 = ld4(&P[(k + kk) * 128 + cq]);
            f4 b2 = ld4(&S[(k + kk) * 128 + cq]);
            float aa = av[kk];
            a1.x += aa * b1.x; a1.y += aa * b1.y; a1.z += aa * b1.z; a1.w += aa * b1.w;
            a2.x += aa * b2.x; a2.y += aa * b2.y; a2.z += aa * b2.z; a2.w += aa * b2.w;
        }
    }
    *(f4*)&gP2[g * 16384 + row * 128 + cq] = a1;
    *(f4*)&gPS[g * 16384 + row * 128 + cq] = a2;
}

// ---------------- K5: P = 1.5P - 0.5*(P2@PS); final iter also emits bf16 W ----------------
__global__ __launch_bounds__(256) void k_ns2(
    float* __restrict__ gP, const float* __restrict__ gP2, const float* __restrict__ gPS,
    const float* __restrict__ gScale, ushort* __restrict__ gWb, int writeW)
{
    int g = blockIdx.y;
    int row = blockIdx.x * 8 + (threadIdx.x >> 5);
    int cq = (threadIdx.x & 31) * 4;
    const float* A = gP2 + g * 16384;
    const float* B = gPS + g * 16384;
    f4 acc = {0.f,0.f,0.f,0.f};
    for (int k = 0; k < 128; k += 4) {
        f4 a = ld4(&A[row * 128 + k]);
        float av[4] = {a.x, a.y, a.z, a.w};
#pragma unroll
        for (int kk = 0; kk < 4; ++kk) {
            f4 b = ld4(&B[(k + kk) * 128 + cq]);
            float aa = av[kk];
            acc.x += aa * b.x; acc.y += aa * b.y; acc.z += aa * b.z; acc.w += aa * b.w;
        }
    }
    size_t off = (size_t)g * 16384 + row * 128 + cq;
    f4 p = ld4(&gP[off]);
    f4 r;
    r.x = 1.5f * p.x - 0.5f * acc.x;
    r.y = 1.5f * p.y - 0.5f * acc.y;
    r.z = 1.5f * p.z - 0.5f * acc.z;
    r.w = 1.5f * p.w - 0.5f * acc.w;
    *(f4*)&gP[off] = r;
    if (writeW) {
        float sc = gScale[g];
        uint32_t lo = pk2(r.x * sc, r.y * sc);
        uint32_t hi = pk2(r.z * sc, r.w * sc);
        *(uint2*)&gWb[off] = make_uint2(lo, hi);
    }
}

// ---------------- K6: beta' = beta - gamma*(W@mu) ----------------
__global__ __launch_bounds__(128) void k_bprime(
    const float* __restrict__ gP, const float* __restrict__ gMean,
    const float* __restrict__ gScale, const float* __restrict__ gamma,
    const float* __restrict__ beta, float* __restrict__ gBp)
{
    int g = blockIdx.x, j = threadIdx.x;
    float s = 0.f;
    for (int k = 0; k < 128; ++k)
        s += gMean[g * 128 + k] * gP[g * 16384 + k * 128 + j];
    s *= gScale[g];
    int c = g * 128 + j;
    gBp[c] = beta[c] - gamma[c] * s;
}

// ---------------- K7: out = gamma*(bf16(X)@W) + beta' ----------------
// Persistent waves: grid (144, 4), block 256 (4 waves). Each wave: 4 consecutive
// 32-sample tiles, 1-deep register prefetch of A; W staged once in LDS
// (XOR-swizzled 16B slots) so W reads use lgkmcnt and never drain the vmcnt
// prefetch queue. 144*4waves*4tiles*32 = 73728.
__global__ __launch_bounds__(256) void k_apply(
    const float* __restrict__ x, const ushort* __restrict__ gWb,
    const float* __restrict__ gamma, const float* __restrict__ gBp,
    float* __restrict__ out)
{
    const int g = blockIdx.y;
    const int t = threadIdx.x, lane = t & 63, w = t >> 6;
    const int l31 = lane & 31, hi = lane >> 5;

    __shared__ ushort Wl[16384];   // 32 KB, rows of 256B = 16 slots of 16B

    // stage W (all 2048 x 16B): logical slot s of row -> physical slot s^(row&15)
    {
        const uint4* src = (const uint4*)(gWb + (size_t)g * 16384);
#pragma unroll
        for (int q = 0; q < 8; ++q) {
            int i = q * 256 + t;          // 0..2047
            int row = i >> 4, s = i & 15;
            uint4 v = src[i];
            *(uint4*)&Wl[row * 128 + ((s ^ (row & 15)) * 8)] = v;
        }
    }
    __syncthreads();

    float gm[4], bp[4];
#pragma unroll
    for (int ct = 0; ct < 4; ++ct) {
        int ch = g * MGRP + ct * 32 + l31;
        gm[ct] = gamma[ch];
        bp[ct] = gBp[ch];
    }

    const int base = (blockIdx.x * 4 + w) * 128;
    const float* ap = x + (size_t)(base + l31) * CTOT + g * MGRP + hi * 8;

    f4 st0[8], st1[8];
#pragma unroll
    for (int ks = 0; ks < 8; ++ks) {
        st0[ks] = ld4(ap + ks * 16);
        st1[ks] = ld4(ap + ks * 16 + 4);
    }

#pragma unroll
    for (int tile = 0; tile < 4; ++tile) {
        bf16x8 af[8];
#pragma unroll
        for (int ks = 0; ks < 8; ++ks) {
            union { bf16x8 b; uint32_t u[4]; } cv;
            cv.u[0] = pk2(st0[ks].x, st0[ks].y);
            cv.u[1] = pk2(st0[ks].z, st0[ks].w);
            cv.u[2] = pk2(st1[ks].x, st1[ks].y);
            cv.u[3] = pk2(st1[ks].z, st1[ks].w);
            af[ks] = cv.b;
        }
        if (tile < 3) {   // prefetch next tile's A while computing this one
            const float* np = ap + (size_t)(tile + 1) * 32 * CTOT;
#pragma unroll
            for (int ks = 0; ks < 8; ++ks) {
                st0[ks] = ld4(np + ks * 16);
                st1[ks] = ld4(np + ks * 16 + 4);
            }
        }
        const int s0 = base + tile * 32;
#pragma unroll
        for (int ct = 0; ct < 4; ++ct) {
            const int row = ct * 32 + l31;
            f32x16 acc = {};
#pragma unroll
            for (int ks = 0; ks < 8; ++ks) {
                int slot = (ks * 2 + hi) ^ (row & 15);
                bf16x8 wf = *(const bf16x8*)&Wl[row * 128 + slot * 8];
                acc = __builtin_amdgcn_mfma_f32_32x32x16_bf16(af[ks], wf, acc, 0, 0, 0);
            }
#pragma unroll
            for (int r = 0; r < 16; ++r) {
                int orow = s0 + (r & 3) + 8 * (r >> 2) + 4 * hi;
                float val = fmaf(gm[ct], acc[r], bp[ct]);
                __builtin_nontemporal_store(val,
                    &out[(size_t)orow * CTOT + g * MGRP + ct * 32 + l31]);
            }
        }
    }
}

// ---------------- launch ----------------
extern "C" void kernel_launch(void* const* d_in, const int* in_sizes, int n_in,
                              void* d_out, int out_size, void* d_ws, size_t ws_size,
                              hipStream_t stream)
{
    const float* x     = (const float*)d_in[0];
    const float* gamma = (const float*)d_in[1];
    const float* beta  = (const float*)d_in[2];
    float* out = (float*)d_out;
    float* ws  = (float*)d_ws;

    int nchunk = 128;   // rowsPer = 576 (divisible by 16)
    auto need = [](int nc) -> size_t {
        return ((size_t)nc * 4 * 16384 + (size_t)nc * 4 * 128 +
                5ull * 4 * 16384 + 512 + 16 + 512 + 32768) * 4;
    };
    while (nchunk > 16 && need(nchunk) > ws_size) nchunk >>= 1;
    int rowsPer = NTOT / nchunk;

    size_t off = 0;
    float* sxxPart = ws + off; off += (size_t)nchunk * 4 * 16384;
    float* sxPart  = ws + off; off += (size_t)nchunk * 4 * 128;
    float* gSxx    = ws + off; off += 4 * 16384;
    float* gSigma  = ws + off; off += 4 * 16384;
    float* gP      = ws + off; off += 4 * 16384;
    float* gP2     = ws + off; off += 4 * 16384;
    float* gPS     = ws + off; off += 4 * 16384;
    float* gMean   = ws + off; off += 512;
    float* gScale  = ws + off; off += 16;
    float* gBp     = ws + off; off += 512;
    ushort* gWb    = (ushort*)(ws + off); off += 32768;   // 4*16384 bf16 = 32768 float-slots

    k_cov<<<dim3(nchunk, 4), 256, 0, stream>>>(x, sxxPart, sxPart, nchunk, rowsPer);
    k_reduce<<<dim3(64, 4), 256, 0, stream>>>(sxxPart, gSxx, nchunk);
    k_finalize<<<4, 256, 0, stream>>>(gSxx, sxPart, gSigma, gP, gMean, gScale, nchunk);
    k_ns1<<<dim3(16, 4), 256, 0, stream>>>(gP, gSigma, gP2, gPS);
    k_ns2<<<dim3(16, 4), 256, 0, stream>>>(gP, gP2, gPS, gScale, gWb, 0);
    k_ns1<<<dim3(16, 4), 256, 0, stream>>>(gP, gSigma, gP2, gPS);
    k_ns2<<<dim3(16, 4), 256, 0, stream>>>(gP, gP2, gPS, gScale, gWb, 1);
    k_bprime<<<4, 128, 0, stream>>>(gP, gMean, gScale, gamma, beta, gBp);
    k_apply<<<dim3(144, 4), 256, 0, stream>>>(x, gWb, gamma, gBp, out);
}

// Round 13
// 175.471 us; speedup vs baseline: 1.2659x; 1.1245x over previous
//
#include <hip/hip_runtime.h>
#include <hip/hip_bf16.h>
#include <cstdint>

#define NTOT 73728      // B*H*W = 32*48*48
#define CTOT 512
#define MGRP 128        // members per group
#define EPSV 1e-7f

typedef float4 f4;
typedef __attribute__((ext_vector_type(8))) short bf16x8;   // 8 bf16 (4 VGPRs)
typedef __attribute__((ext_vector_type(4))) float f32x4;
typedef __attribute__((ext_vector_type(16))) float f32x16;

__device__ __forceinline__ f4 ld4(const float* p){ return *(const f4*)p; }

__device__ __forceinline__ ushort f2bf(float f){  // RNE fp32 -> bf16 (cold paths)
    uint32_t u = __builtin_bit_cast(uint32_t, f);
    uint32_t r = (u + 0x7FFFu + ((u >> 16) & 1u)) >> 16;
    return (ushort)r;
}

__device__ __forceinline__ uint32_t pk2(float a, float b){   // HW v_cvt_pk_bf16_f32
    __hip_bfloat162 h = __float22bfloat162_rn(make_float2(a, b));
    uint32_t u; __builtin_memcpy(&u, &h, 4);
    return u;
}

__device__ __forceinline__ bf16x8 pack8(const float v[8]) {
    union { bf16x8 b; uint32_t u[4]; } r;
#pragma unroll
    for (int i = 0; i < 4; ++i) r.u[i] = pk2(v[2*i], v[2*i+1]);
    return r.b;
}

// ---------------- K1: Sxx partials — coalesced ld4 staging + LDS-transposed frags --------
// grid (nchunk, 4), block 256 (4 waves 2x2; wave tile 64x64 of 128x128, r12 mapping).
// K-tile = 16 samples: LDS fp32 [16][128] (8 KB), double-buffered, 1 barrier/iter.
// Staging: thread t loads float4 at (sample t>>5 / +8, chunk t&31) -> 8 full lines/instr.
// Frag reads: ds_read_b32 [hi*8+e][ch] — lanes = consecutive ch -> conflict-free.
__global__ __launch_bounds__(256) void k_cov(
    const float* __restrict__ x, float* __restrict__ sxxPart,
    float* __restrict__ sxPart, int nchunk, int rowsPer)
{
    const int chunk = blockIdx.x, g = blockIdx.y;
    const int t = threadIdx.x;
    const int lane = t & 63, wid = t >> 6;
    const int wr = wid >> 1, wc = wid & 1;
    const int l31 = lane & 31, hi = lane >> 5;
    const size_t rowbase = (size_t)chunk * rowsPer;

    __shared__ float xs[2][16][128];   // 2 x 8 KB
    __shared__ float sxred[256];

    const int ssmp = t >> 5;           // staging sample 0..7 (and +8)
    const int schk = t & 31;           // staging chunk (4 floats)
    const float* xp = x + (size_t)g * MGRP + (size_t)schk * 4;

    f32x16 acc[2][2];
#pragma unroll
    for (int a = 0; a < 2; ++a)
#pragma unroll
        for (int b = 0; b < 2; ++b) acc[a][b] = (f32x16){};
    float sxa0 = 0.f, sxa1 = 0.f;

    const int niter = rowsPer / 16;
    f4 r0 = ld4(xp + (rowbase + ssmp) * CTOT);
    f4 r1 = ld4(xp + (rowbase + 8 + ssmp) * CTOT);

    for (int it = 0; it < niter; ++it) {
        const int cur = it & 1;
        *(f32x4*)&xs[cur][ssmp][schk * 4]     = (f32x4){r0.x, r0.y, r0.z, r0.w};
        *(f32x4*)&xs[cur][8 + ssmp][schk * 4] = (f32x4){r1.x, r1.y, r1.z, r1.w};
        __syncthreads();                 // single barrier/iter (dbuf-safe, see r6)
        if (it + 1 < niter) {            // prefetch next tile (in flight under compute)
            const float* np = xp + (rowbase + (size_t)(it + 1) * 16) * CTOT;
            r0 = ld4(np + (size_t)ssmp * CTOT);
            r1 = ld4(np + (size_t)(8 + ssmp) * CTOT);
        }
        bf16x8 fa[2], fb[2];
#pragma unroll
        for (int a = 0; a < 2; ++a) {
            float v[8];
            const int ch = wr * 64 + a * 32 + l31;
#pragma unroll
            for (int e = 0; e < 8; ++e) v[e] = xs[cur][hi * 8 + e][ch];
            if (wc == 0) {
                float s = 0.f;
#pragma unroll
                for (int e = 0; e < 8; ++e) s += v[e];
                if (a == 0) sxa0 += s; else sxa1 += s;
            }
            fa[a] = pack8(v);
        }
        if (wr != wc) {
#pragma unroll
            for (int b = 0; b < 2; ++b) {
                float v[8];
                const int ch = wc * 64 + b * 32 + l31;
#pragma unroll
                for (int e = 0; e < 8; ++e) v[e] = xs[cur][hi * 8 + e][ch];
                fb[b] = pack8(v);
            }
        } else {
            fb[0] = fa[0]; fb[1] = fa[1];
        }
#pragma unroll
        for (int a = 0; a < 2; ++a)
#pragma unroll
            for (int b = 0; b < 2; ++b)
                acc[a][b] = __builtin_amdgcn_mfma_f32_32x32x16_bf16(
                    fa[a], fb[b], acc[a][b], 0, 0, 0);
    }

    float* op = sxxPart + ((size_t)g * nchunk + chunk) * 16384;
#pragma unroll
    for (int a = 0; a < 2; ++a)
#pragma unroll
        for (int b = 0; b < 2; ++b)
#pragma unroll
            for (int r = 0; r < 16; ++r) {
                int i = wr*64 + a*32 + (r & 3) + 8 * (r >> 2) + 4 * hi;
                int j = wc*64 + b*32 + l31;
                op[i * 128 + j] = acc[a][b][r];
            }

    if (wc == 0) {
        sxred[(wr*64 + l31) * 2 + hi]      = sxa0;
        sxred[(wr*64 + 32 + l31) * 2 + hi] = sxa1;
    }
    __syncthreads();
    if (t < 128)
        sxPart[((size_t)g * nchunk + chunk) * 128 + t] = sxred[t*2] + sxred[t*2 + 1];
}

// ---------------- K2: reduce Sxx partials over chunks ----------------
__global__ __launch_bounds__(256) void k_reduce(
    const float* __restrict__ sxxPart, float* __restrict__ gSxx, int nchunk)
{
    int g = blockIdx.y;
    int idx = blockIdx.x * 256 + threadIdx.x;
    float s = 0.f;
#pragma unroll 8
    for (int c = 0; c < nchunk; ++c)
        s += sxxPart[((size_t)g * nchunk + c) * 16384 + idx];
    gSxx[g * 16384 + idx] = s;
}

// ---------------- K3: finalize -> mean, trace, sigma, P1 ----------------
__global__ __launch_bounds__(256) void k_finalize(
    const float* __restrict__ gSxx, const float* __restrict__ sxPart,
    float* __restrict__ gSigma, float* __restrict__ gP,
    float* __restrict__ gMean, float* __restrict__ gScale, int nchunk)
{
    int g = blockIdx.x, t = threadIdx.x;
    __shared__ float mu[128];
    __shared__ float red[256];

    if (t < 128) {
        float s = 0.f;
        for (int c = 0; c < nchunk; ++c)
            s += sxPart[((size_t)g * nchunk + c) * 128 + t];
        float m = s / (float)NTOT;
        mu[t] = m;
        gMean[g * 128 + t] = m;
    }
    __syncthreads();

    float d = 0.f;
    if (t < 128) {
        float vdiag = gSxx[g * 16384 + t * 128 + t];
        float cv = (vdiag - (float)NTOT * mu[t] * mu[t]) / ((float)NTOT - 1.f);
        d = (1.f - EPSV) * cv + EPSV;
    }
    red[t] = d;
    __syncthreads();
    for (int s = 128; s > 0; s >>= 1) {
        if (t < s) red[t] += red[t + s];
        __syncthreads();
    }
    float tr = red[0];
    float invTr = 1.f / tr;
    if (t == 0) gScale[g] = rsqrtf(tr);

    for (int e = t; e < 16384; e += 256) {
        int i = e >> 7, j = e & 127;
        float cv = (gSxx[g * 16384 + e] - (float)NTOT * mu[i] * mu[j]) / ((float)NTOT - 1.f);
        float ce = (1.f - EPSV) * cv + ((i == j) ? EPSV : 0.f);
        float sg = ce * invTr;
        gSigma[g * 16384 + e] = sg;
        gP[g * 16384 + e] = ((i == j) ? 1.5f : 0.f) - 0.5f * sg;
    }
}

// ---------------- K4: P2 = P@P, PS = P@Sigma ----------------
__global__ __launch_bounds__(256) void k_ns1(
    const float* __restrict__ gP, const float* __restrict__ gS,
    float* __restrict__ gP2, float* __restrict__ gPS)
{
    int g = blockIdx.y;
    int row = blockIdx.x * 8 + (threadIdx.x >> 5);
    int cq = (threadIdx.x & 31) * 4;
    const float* P = gP + g * 16384;
    const float* S = gS + g * 16384;
    f4 a1 = {0.f,0.f,0.f,0.f}, a2 = {0.f,0.f,0.f,0.f};
    for (int k = 0; k < 128; k += 4) {
        f4 a = ld4(&P[row * 128 + k]);
        float av[4] = {a.x, a.y, a.z, a.w};
#pragma unroll
        for (int kk = 0; kk < 4; ++kk) {
            f4 b1 = ld4(&P[(k + kk) * 128 + cq]);
            f4 b2 = ld4(&S[(k + kk) * 128 + cq]);
            float aa = av[kk];
            a1.x += aa * b1.x; a1.y += aa * b1.y; a1.z += aa * b1.z; a1.w += aa * b1.w;
            a2.x += aa * b2.x; a2.y += aa * b2.y; a2.z += aa * b2.z; a2.w += aa * b2.w;
        }
    }
    *(f4*)&gP2[g * 16384 + row * 128 + cq] = a1;
    *(f4*)&gPS[g * 16384 + row * 128 + cq] = a2;
}

// ---------------- K5: P = 1.5P - 0.5*(P2@PS); final iter also emits bf16 W ----------------
__global__ __launch_bounds__(256) void k_ns2(
    float* __restrict__ gP, const float* __restrict__ gP2, const float* __restrict__ gPS,
    const float* __restrict__ gScale, ushort* __restrict__ gWb, int writeW)
{
    int g = blockIdx.y;
    int row = blockIdx.x * 8 + (threadIdx.x >> 5);
    int cq = (threadIdx.x & 31) * 4;
    const float* A = gP2 + g * 16384;
    const float* B = gPS + g * 16384;
    f4 acc = {0.f,0.f,0.f,0.f};
    for (int k = 0; k < 128; k += 4) {
        f4 a = ld4(&A[row * 128 + k]);
        float av[4] = {a.x, a.y, a.z, a.w};
#pragma unroll
        for (int kk = 0; kk < 4; ++kk) {
            f4 b = ld4(&B[(k + kk) * 128 + cq]);
            float aa = av[kk];
            acc.x += aa * b.x; acc.y += aa * b.y; acc.z += aa * b.z; acc.w += aa * b.w;
        }
    }
    size_t off = (size_t)g * 16384 + row * 128 + cq;
    f4 p = ld4(&gP[off]);
    f4 r;
    r.x = 1.5f * p.x - 0.5f * acc.x;
    r.y = 1.5f * p.y - 0.5f * acc.y;
    r.z = 1.5f * p.z - 0.5f * acc.z;
    r.w = 1.5f * p.w - 0.5f * acc.w;
    *(f4*)&gP[off] = r;
    if (writeW) {
        float sc = gScale[g];
        uint32_t lo = pk2(r.x * sc, r.y * sc);
        uint32_t hi = pk2(r.z * sc, r.w * sc);
        *(uint2*)&gWb[off] = make_uint2(lo, hi);
    }
}

// ---------------- K6: beta' = beta - gamma*(W@mu) ----------------
__global__ __launch_bounds__(128) void k_bprime(
    const float* __restrict__ gP, const float* __restrict__ gMean,
    const float* __restrict__ gScale, const float* __restrict__ gamma,
    const float* __restrict__ beta, float* __restrict__ gBp)
{
    int g = blockIdx.x, j = threadIdx.x;
    float s = 0.f;
    for (int k = 0; k < 128; ++k)
        s += gMean[g * 128 + k] * gP[g * 16384 + k * 128 + j];
    s *= gScale[g];
    int c = g * 128 + j;
    gBp[c] = beta[c] - gamma[c] * s;
}

// ---------------- K7: out = gamma*(bf16(X)@W) + beta' ----------------
// Persistent waves: grid (144, 4), block 256 (4 waves). Each wave: 4 consecutive
// 32-sample tiles, 1-deep register prefetch of A; W staged once in LDS
// (XOR-swizzled 16B slots). 144*4waves*4tiles*32 = 73728.  [unchanged from r12]
__global__ __launch_bounds__(256) void k_apply(
    const float* __restrict__ x, const ushort* __restrict__ gWb,
    const float* __restrict__ gamma, const float* __restrict__ gBp,
    float* __restrict__ out)
{
    const int g = blockIdx.y;
    const int t = threadIdx.x, lane = t & 63, w = t >> 6;
    const int l31 = lane & 31, hi = lane >> 5;

    __shared__ ushort Wl[16384];   // 32 KB, rows of 256B = 16 slots of 16B

    // stage W (all 2048 x 16B): logical slot s of row -> physical slot s^(row&15)
    {
        const uint4* src = (const uint4*)(gWb + (size_t)g * 16384);
#pragma unroll
        for (int q = 0; q < 8; ++q) {
            int i = q * 256 + t;          // 0..2047
            int row = i >> 4, s = i & 15;
            uint4 v = src[i];
            *(uint4*)&Wl[row * 128 + ((s ^ (row & 15)) * 8)] = v;
        }
    }
    __syncthreads();

    float gm[4], bp[4];
#pragma unroll
    for (int ct = 0; ct < 4; ++ct) {
        int ch = g * MGRP + ct * 32 + l31;
        gm[ct] = gamma[ch];
        bp[ct] = gBp[ch];
    }

    const int base = (blockIdx.x * 4 + w) * 128;
    const float* ap = x + (size_t)(base + l31) * CTOT + g * MGRP + hi * 8;

    f4 st0[8], st1[8];
#pragma unroll
    for (int ks = 0; ks < 8; ++ks) {
        st0[ks] = ld4(ap + ks * 16);
        st1[ks] = ld4(ap + ks * 16 + 4);
    }

#pragma unroll
    for (int tile = 0; tile < 4; ++tile) {
        bf16x8 af[8];
#pragma unroll
        for (int ks = 0; ks < 8; ++ks) {
            union { bf16x8 b; uint32_t u[4]; } cv;
            cv.u[0] = pk2(st0[ks].x, st0[ks].y);
            cv.u[1] = pk2(st0[ks].z, st0[ks].w);
            cv.u[2] = pk2(st1[ks].x, st1[ks].y);
            cv.u[3] = pk2(st1[ks].z, st1[ks].w);
            af[ks] = cv.b;
        }
        if (tile < 3) {
            const float* np = ap + (size_t)(tile + 1) * 32 * CTOT;
#pragma unroll
            for (int ks = 0; ks < 8; ++ks) {
                st0[ks] = ld4(np + ks * 16);
                st1[ks] = ld4(np + ks * 16 + 4);
            }
        }
        const int s0 = base + tile * 32;
#pragma unroll
        for (int ct = 0; ct < 4; ++ct) {
            const int row = ct * 32 + l31;
            f32x16 acc = {};
#pragma unroll
            for (int ks = 0; ks < 8; ++ks) {
                int slot = (ks * 2 + hi) ^ (row & 15);
                bf16x8 wf = *(const bf16x8*)&Wl[row * 128 + slot * 8];
                acc = __builtin_amdgcn_mfma_f32_32x32x16_bf16(af[ks], wf, acc, 0, 0, 0);
            }
#pragma unroll
            for (int r = 0; r < 16; ++r) {
                int orow = s0 + (r & 3) + 8 * (r >> 2) + 4 * hi;
                float val = fmaf(gm[ct], acc[r], bp[ct]);
                __builtin_nontemporal_store(val,
                    &out[(size_t)orow * CTOT + g * MGRP + ct * 32 + l31]);
            }
        }
    }
}

// ---------------- launch ----------------
extern "C" void kernel_launch(void* const* d_in, const int* in_sizes, int n_in,
                              void* d_out, int out_size, void* d_ws, size_t ws_size,
                              hipStream_t stream)
{
    const float* x     = (const float*)d_in[0];
    const float* gamma = (const float*)d_in[1];
    const float* beta  = (const float*)d_in[2];
    float* out = (float*)d_out;
    float* ws  = (float*)d_ws;

    int nchunk = 128;   // rowsPer = 576 (divisible by 16)
    auto need = [](int nc) -> size_t {
        return ((size_t)nc * 4 * 16384 + (size_t)nc * 4 * 128 +
                5ull * 4 * 16384 + 512 + 16 + 512 + 32768) * 4;
    };
    while (nchunk > 16 && need(nchunk) > ws_size) nchunk >>= 1;
    int rowsPer = NTOT / nchunk;

    size_t off = 0;
    float* sxxPart = ws + off; off += (size_t)nchunk * 4 * 16384;
    float* sxPart  = ws + off; off += (size_t)nchunk * 4 * 128;
    float* gSxx    = ws + off; off += 4 * 16384;
    float* gSigma  = ws + off; off += 4 * 16384;
    float* gP      = ws + off; off += 4 * 16384;
    float* gP2     = ws + off; off += 4 * 16384;
    float* gPS     = ws + off; off += 4 * 16384;
    float* gMean   = ws + off; off += 512;
    float* gScale  = ws + off; off += 16;
    float* gBp     = ws + off; off += 512;
    ushort* gWb    = (ushort*)(ws + off); off += 32768;   // 4*16384 bf16 = 32768 float-slots

    k_cov<<<dim3(nchunk, 4), 256, 0, stream>>>(x, sxxPart, sxPart, nchunk, rowsPer);
    k_reduce<<<dim3(64, 4), 256, 0, stream>>>(sxxPart, gSxx, nchunk);
    k_finalize<<<4, 256, 0, stream>>>(gSxx, sxPart, gSigma, gP, gMean, gScale, nchunk);
    k_ns1<<<dim3(16, 4), 256, 0, stream>>>(gP, gSigma, gP2, gPS);
    k_ns2<<<dim3(16, 4), 256, 0, stream>>>(gP, gP2, gPS, gScale, gWb, 0);
    k_ns1<<<dim3(16, 4), 256, 0, stream>>>(gP, gSigma, gP2, gPS);
    k_ns2<<<dim3(16, 4), 256, 0, stream>>>(gP, gP2, gPS, gScale, gWb, 1);
    k_bprime<<<4, 128, 0, stream>>>(gP, gMean, gScale, gamma, beta, gBp);
    k_apply<<<dim3(144, 4), 256, 0, stream>>>(x, gWb, gamma, gBp, out);
}

// Round 14
// 174.728 us; speedup vs baseline: 1.2713x; 1.0043x over previous
//
#include <hip/hip_runtime.h>
#include <hip/hip_bf16.h>
#include <cstdint>

#define NTOT 73728      // B*H*W = 32*48*48
#define CTOT 512
#define MGRP 128        // members per group
#define EPSV 1e-7f

typedef float4 f4;
typedef __attribute__((ext_vector_type(8))) short bf16x8;   // 8 bf16 (4 VGPRs)
typedef __attribute__((ext_vector_type(4))) float f32x4;
typedef __attribute__((ext_vector_type(16))) float f32x16;

__device__ __forceinline__ f4 ld4(const float* p){ return *(const f4*)p; }

__device__ __forceinline__ uint32_t pk2(float a, float b){   // HW v_cvt_pk_bf16_f32
    __hip_bfloat162 h = __float22bfloat162_rn(make_float2(a, b));
    uint32_t u; __builtin_memcpy(&u, &h, 4);
    return u;
}

__device__ __forceinline__ bf16x8 pack8(const float v[8]) {
    union { bf16x8 b; uint32_t u[4]; } r;
#pragma unroll
    for (int i = 0; i < 4; ++i) r.u[i] = pk2(v[2*i], v[2*i+1]);
    return r.b;
}

// ---------------- K1: Sxx partials — 32-sample K-tiles, 1 barrier/tile ----------------
// grid (nchunk, 4), block 256 (4 waves 2x2; wave tile 64x64 of 128x128, r12 mapping).
// LDS fp32 [32][128] (16 KB), double-buffered. Staging: 4 coalesced ld4/thread.
// Frag reads: b32 [k][ch] — lanes = consecutive ch -> conflict-free. 8 MFMA/wave/tile.
__global__ __launch_bounds__(256) void k_cov(
    const float* __restrict__ x, float* __restrict__ sxxPart,
    float* __restrict__ sxPart, int nchunk, int rowsPer)
{
    const int chunk = blockIdx.x, g = blockIdx.y;
    const int t = threadIdx.x;
    const int lane = t & 63, wid = t >> 6;
    const int wr = wid >> 1, wc = wid & 1;
    const int l31 = lane & 31, hi = lane >> 5;
    const size_t rowbase = (size_t)chunk * rowsPer;

    __shared__ float xs[2][32][128];   // 2 x 16 KB
    __shared__ float sxred[256];

    const int ssmp = t >> 5;           // staging sample 0..7 (+8,+16,+24)
    const int schk = t & 31;           // staging chunk (4 floats)
    const float* xp = x + (size_t)g * MGRP + (size_t)schk * 4;

    f32x16 acc[2][2];
#pragma unroll
    for (int a = 0; a < 2; ++a)
#pragma unroll
        for (int b = 0; b < 2; ++b) acc[a][b] = (f32x16){};
    float sxa0 = 0.f, sxa1 = 0.f;

    const int niter = rowsPer / 32;
    f4 r0 = ld4(xp + (rowbase + ssmp) * CTOT);
    f4 r1 = ld4(xp + (rowbase + 8 + ssmp) * CTOT);
    f4 r2 = ld4(xp + (rowbase + 16 + ssmp) * CTOT);
    f4 r3 = ld4(xp + (rowbase + 24 + ssmp) * CTOT);

    for (int it = 0; it < niter; ++it) {
        const int cur = it & 1;
        *(f32x4*)&xs[cur][ssmp][schk * 4]      = (f32x4){r0.x, r0.y, r0.z, r0.w};
        *(f32x4*)&xs[cur][8 + ssmp][schk * 4]  = (f32x4){r1.x, r1.y, r1.z, r1.w};
        *(f32x4*)&xs[cur][16 + ssmp][schk * 4] = (f32x4){r2.x, r2.y, r2.z, r2.w};
        *(f32x4*)&xs[cur][24 + ssmp][schk * 4] = (f32x4){r3.x, r3.y, r3.z, r3.w};
        __syncthreads();                 // single barrier/tile (dbuf)
        if (it + 1 < niter) {            // prefetch next tile (in flight under compute)
            const float* np = xp + (rowbase + (size_t)(it + 1) * 32) * CTOT;
            r0 = ld4(np + (size_t)ssmp * CTOT);
            r1 = ld4(np + (size_t)(8 + ssmp) * CTOT);
            r2 = ld4(np + (size_t)(16 + ssmp) * CTOT);
            r3 = ld4(np + (size_t)(24 + ssmp) * CTOT);
        }
#pragma unroll
        for (int ks = 0; ks < 2; ++ks) {         // two 16-sample k-slices
            bf16x8 fa[2], fb[2];
#pragma unroll
            for (int a = 0; a < 2; ++a) {
                float v[8];
                const int ch = wr * 64 + a * 32 + l31;
#pragma unroll
                for (int e = 0; e < 8; ++e) v[e] = xs[cur][ks * 16 + hi * 8 + e][ch];
                if (wc == 0) {
                    float s = 0.f;
#pragma unroll
                    for (int e = 0; e < 8; ++e) s += v[e];
                    if (a == 0) sxa0 += s; else sxa1 += s;
                }
                fa[a] = pack8(v);
            }
            if (wr != wc) {
#pragma unroll
                for (int b = 0; b < 2; ++b) {
                    float v[8];
                    const int ch = wc * 64 + b * 32 + l31;
#pragma unroll
                    for (int e = 0; e < 8; ++e) v[e] = xs[cur][ks * 16 + hi * 8 + e][ch];
                    fb[b] = pack8(v);
                }
            } else {
                fb[0] = fa[0]; fb[1] = fa[1];
            }
#pragma unroll
            for (int a = 0; a < 2; ++a)
#pragma unroll
                for (int b = 0; b < 2; ++b)
                    acc[a][b] = __builtin_amdgcn_mfma_f32_32x32x16_bf16(
                        fa[a], fb[b], acc[a][b], 0, 0, 0);
        }
    }

    float* op = sxxPart + ((size_t)g * nchunk + chunk) * 16384;
#pragma unroll
    for (int a = 0; a < 2; ++a)
#pragma unroll
        for (int b = 0; b < 2; ++b)
#pragma unroll
            for (int r = 0; r < 16; ++r) {
                int i = wr*64 + a*32 + (r & 3) + 8 * (r >> 2) + 4 * hi;
                int j = wc*64 + b*32 + l31;
                op[i * 128 + j] = acc[a][b][r];
            }

    if (wc == 0) {
        sxred[(wr*64 + l31) * 2 + hi]      = sxa0;
        sxred[(wr*64 + 32 + l31) * 2 + hi] = sxa1;
    }
    __syncthreads();
    if (t < 128)
        sxPart[((size_t)g * nchunk + chunk) * 128 + t] = sxred[t*2] + sxred[t*2 + 1];
}

// ---------------- K2: reduce Sxx partials over chunks ----------------
__global__ __launch_bounds__(256) void k_reduce(
    const float* __restrict__ sxxPart, float* __restrict__ gSxx, int nchunk)
{
    int g = blockIdx.y;
    int idx = blockIdx.x * 256 + threadIdx.x;
    float s = 0.f;
#pragma unroll 8
    for (int c = 0; c < nchunk; ++c)
        s += sxxPart[((size_t)g * nchunk + c) * 16384 + idx];
    gSxx[g * 16384 + idx] = s;
}

// ---------------- K3: finalize -> mean, trace, sigma, P1 ----------------
__global__ __launch_bounds__(256) void k_finalize(
    const float* __restrict__ gSxx, const float* __restrict__ sxPart,
    float* __restrict__ gSigma, float* __restrict__ gP,
    float* __restrict__ gMean, float* __restrict__ gScale, int nchunk)
{
    int g = blockIdx.x, t = threadIdx.x;
    __shared__ float mu[128];
    __shared__ float red[256];

    if (t < 128) {
        float s = 0.f;
        for (int c = 0; c < nchunk; ++c)
            s += sxPart[((size_t)g * nchunk + c) * 128 + t];
        float m = s / (float)NTOT;
        mu[t] = m;
        gMean[g * 128 + t] = m;
    }
    __syncthreads();

    float d = 0.f;
    if (t < 128) {
        float vdiag = gSxx[g * 16384 + t * 128 + t];
        float cv = (vdiag - (float)NTOT * mu[t] * mu[t]) / ((float)NTOT - 1.f);
        d = (1.f - EPSV) * cv + EPSV;
    }
    red[t] = d;
    __syncthreads();
    for (int s = 128; s > 0; s >>= 1) {
        if (t < s) red[t] += red[t + s];
        __syncthreads();
    }
    float tr = red[0];
    float invTr = 1.f / tr;
    if (t == 0) gScale[g] = rsqrtf(tr);

    for (int e = t; e < 16384; e += 256) {
        int i = e >> 7, j = e & 127;
        float cv = (gSxx[g * 16384 + e] - (float)NTOT * mu[i] * mu[j]) / ((float)NTOT - 1.f);
        float ce = (1.f - EPSV) * cv + ((i == j) ? EPSV : 0.f);
        float sg = ce * invTr;
        gSigma[g * 16384 + e] = sg;
        gP[g * 16384 + e] = ((i == j) ? 1.5f : 0.f) - 0.5f * sg;
    }
}

// ---------------- K4: P2 = P@P, PS = P@Sigma ----------------
__global__ __launch_bounds__(256) void k_ns1(
    const float* __restrict__ gP, const float* __restrict__ gS,
    float* __restrict__ gP2, float* __restrict__ gPS)
{
    int g = blockIdx.y;
    int row = blockIdx.x * 8 + (threadIdx.x >> 5);
    int cq = (threadIdx.x & 31) * 4;
    const float* P = gP + g * 16384;
    const float* S = gS + g * 16384;
    f4 a1 = {0.f,0.f,0.f,0.f}, a2 = {0.f,0.f,0.f,0.f};
    for (int k = 0; k < 128; k += 4) {
        f4 a = ld4(&P[row * 128 + k]);
        float av[4] = {a.x, a.y, a.z, a.w};
#pragma unroll
        for (int kk = 0; kk < 4; ++kk) {
            f4 b1 = ld4(&P[(k + kk) * 128 + cq]);
            f4 b2 = ld4(&S[(k + kk) * 128 + cq]);
            float aa = av[kk];
            a1.x += aa * b1.x; a1.y += aa * b1.y; a1.z += aa * b1.z; a1.w += aa * b1.w;
            a2.x += aa * b2.x; a2.y += aa * b2.y; a2.z += aa * b2.z; a2.w += aa * b2.w;
        }
    }
    *(f4*)&gP2[g * 16384 + row * 128 + cq] = a1;
    *(f4*)&gPS[g * 16384 + row * 128 + cq] = a2;
}

// ---------------- K5: P = 1.5P - 0.5*(P2@PS); final iter also emits bf16 W ----------------
__global__ __launch_bounds__(256) void k_ns2(
    float* __restrict__ gP, const float* __restrict__ gP2, const float* __restrict__ gPS,
    const float* __restrict__ gScale, ushort* __restrict__ gWb, int writeW)
{
    int g = blockIdx.y;
    int row = blockIdx.x * 8 + (threadIdx.x >> 5);
    int cq = (threadIdx.x & 31) * 4;
    const float* A = gP2 + g * 16384;
    const float* B = gPS + g * 16384;
    f4 acc = {0.f,0.f,0.f,0.f};
    for (int k = 0; k < 128; k += 4) {
        f4 a = ld4(&A[row * 128 + k]);
        float av[4] = {a.x, a.y, a.z, a.w};
#pragma unroll
        for (int kk = 0; kk < 4; ++kk) {
            f4 b = ld4(&B[(k + kk) * 128 + cq]);
            float aa = av[kk];
            acc.x += aa * b.x; acc.y += aa * b.y; acc.z += aa * b.z; acc.w += aa * b.w;
        }
    }
    size_t off = (size_t)g * 16384 + row * 128 + cq;
    f4 p = ld4(&gP[off]);
    f4 r;
    r.x = 1.5f * p.x - 0.5f * acc.x;
    r.y = 1.5f * p.y - 0.5f * acc.y;
    r.z = 1.5f * p.z - 0.5f * acc.z;
    r.w = 1.5f * p.w - 0.5f * acc.w;
    *(f4*)&gP[off] = r;
    if (writeW) {
        float sc = gScale[g];
        uint32_t lo = pk2(r.x * sc, r.y * sc);
        uint32_t hi = pk2(r.z * sc, r.w * sc);
        *(uint2*)&gWb[off] = make_uint2(lo, hi);
    }
}

// ---------------- K6: beta' = beta - gamma*(W@mu) ----------------
__global__ __launch_bounds__(128) void k_bprime(
    const float* __restrict__ gP, const float* __restrict__ gMean,
    const float* __restrict__ gScale, const float* __restrict__ gamma,
    const float* __restrict__ beta, float* __restrict__ gBp)
{
    int g = blockIdx.x, j = threadIdx.x;
    float s = 0.f;
    for (int k = 0; k < 128; ++k)
        s += gMean[g * 128 + k] * gP[g * 16384 + k * 128 + j];
    s *= gScale[g];
    int c = g * 128 + j;
    gBp[c] = beta[c] - gamma[c] * s;
}

// ---------------- K7: out = gamma*(bf16(X)@W) + beta' ----------------
// grid (288, 4), block 256 (4 waves). Each wave: 2 consecutive 32-sample tiles,
// 1-deep register prefetch of A; W staged once in LDS (XOR-swizzled 16B slots).
// 288 * 4 waves * 2 tiles * 32 = 73728.  [r12 structure, finer-grained blocks]
__global__ __launch_bounds__(256) void k_apply(
    const float* __restrict__ x, const ushort* __restrict__ gWb,
    const float* __restrict__ gamma, const float* __restrict__ gBp,
    float* __restrict__ out)
{
    const int g = blockIdx.y;
    const int t = threadIdx.x, lane = t & 63, w = t >> 6;
    const int l31 = lane & 31, hi = lane >> 5;

    __shared__ ushort Wl[16384];   // 32 KB, rows of 256B = 16 slots of 16B

    // stage W (all 2048 x 16B): logical slot s of row -> physical slot s^(row&15)
    {
        const uint4* src = (const uint4*)(gWb + (size_t)g * 16384);
#pragma unroll
        for (int q = 0; q < 8; ++q) {
            int i = q * 256 + t;          // 0..2047
            int row = i >> 4, s = i & 15;
            uint4 v = src[i];
            *(uint4*)&Wl[row * 128 + ((s ^ (row & 15)) * 8)] = v;
        }
    }
    __syncthreads();

    float gm[4], bp[4];
#pragma unroll
    for (int ct = 0; ct < 4; ++ct) {
        int ch = g * MGRP + ct * 32 + l31;
        gm[ct] = gamma[ch];
        bp[ct] = gBp[ch];
    }

    const int base = (blockIdx.x * 4 + w) * 64;
    const float* ap = x + (size_t)(base + l31) * CTOT + g * MGRP + hi * 8;

    f4 st0[8], st1[8];
#pragma unroll
    for (int ks = 0; ks < 8; ++ks) {
        st0[ks] = ld4(ap + ks * 16);
        st1[ks] = ld4(ap + ks * 16 + 4);
    }

#pragma unroll
    for (int tile = 0; tile < 2; ++tile) {
        bf16x8 af[8];
#pragma unroll
        for (int ks = 0; ks < 8; ++ks) {
            union { bf16x8 b; uint32_t u[4]; } cv;
            cv.u[0] = pk2(st0[ks].x, st0[ks].y);
            cv.u[1] = pk2(st0[ks].z, st0[ks].w);
            cv.u[2] = pk2(st1[ks].x, st1[ks].y);
            cv.u[3] = pk2(st1[ks].z, st1[ks].w);
            af[ks] = cv.b;
        }
        if (tile < 1) {   // prefetch second tile's A while computing first
            const float* np = ap + (size_t)32 * CTOT;
#pragma unroll
            for (int ks = 0; ks < 8; ++ks) {
                st0[ks] = ld4(np + ks * 16);
                st1[ks] = ld4(np + ks * 16 + 4);
            }
        }
        const int s0 = base + tile * 32;
#pragma unroll
        for (int ct = 0; ct < 4; ++ct) {
            const int row = ct * 32 + l31;
            f32x16 acc = {};
#pragma unroll
            for (int ks = 0; ks < 8; ++ks) {
                int slot = (ks * 2 + hi) ^ (row & 15);
                bf16x8 wf = *(const bf16x8*)&Wl[row * 128 + slot * 8];
                acc = __builtin_amdgcn_mfma_f32_32x32x16_bf16(af[ks], wf, acc, 0, 0, 0);
            }
#pragma unroll
            for (int r = 0; r < 16; ++r) {
                int orow = s0 + (r & 3) + 8 * (r >> 2) + 4 * hi;
                float val = fmaf(gm[ct], acc[r], bp[ct]);
                __builtin_nontemporal_store(val,
                    &out[(size_t)orow * CTOT + g * MGRP + ct * 32 + l31]);
            }
        }
    }
}

// ---------------- launch ----------------
extern "C" void kernel_launch(void* const* d_in, const int* in_sizes, int n_in,
                              void* d_out, int out_size, void* d_ws, size_t ws_size,
                              hipStream_t stream)
{
    const float* x     = (const float*)d_in[0];
    const float* gamma = (const float*)d_in[1];
    const float* beta  = (const float*)d_in[2];
    float* out = (float*)d_out;
    float* ws  = (float*)d_ws;

    int nchunk = 128;   // rowsPer = 576 (divisible by 32)
    auto need = [](int nc) -> size_t {
        return ((size_t)nc * 4 * 16384 + (size_t)nc * 4 * 128 +
                5ull * 4 * 16384 + 512 + 16 + 512 + 32768) * 4;
    };
    while (nchunk > 16 && need(nchunk) > ws_size) nchunk >>= 1;
    int rowsPer = NTOT / nchunk;

    size_t off = 0;
    float* sxxPart = ws + off; off += (size_t)nchunk * 4 * 16384;
    float* sxPart  = ws + off; off += (size_t)nchunk * 4 * 128;
    float* gSxx    = ws + off; off += 4 * 16384;
    float* gSigma  = ws + off; off += 4 * 16384;
    float* gP      = ws + off; off += 4 * 16384;
    float* gP2     = ws + off; off += 4 * 16384;
    float* gPS     = ws + off; off += 4 * 16384;
    float* gMean   = ws + off; off += 512;
    float* gScale  = ws + off; off += 16;
    float* gBp     = ws + off; off += 512;
    ushort* gWb    = (ushort*)(ws + off); off += 32768;   // 4*16384 bf16 = 32768 float-slots

    k_cov<<<dim3(nchunk, 4), 256, 0, stream>>>(x, sxxPart, sxPart, nchunk, rowsPer);
    k_reduce<<<dim3(64, 4), 256, 0, stream>>>(sxxPart, gSxx, nchunk);
    k_finalize<<<4, 256, 0, stream>>>(gSxx, sxPart, gSigma, gP, gMean, gScale, nchunk);
    k_ns1<<<dim3(16, 4), 256, 0, stream>>>(gP, gSigma, gP2, gPS);
    k_ns2<<<dim3(16, 4), 256, 0, stream>>>(gP, gP2, gPS, gScale, gWb, 0);
    k_ns1<<<dim3(16, 4), 256, 0, stream>>>(gP, gSigma, gP2, gPS);
    k_ns2<<<dim3(16, 4), 256, 0, stream>>>(gP, gP2, gPS, gScale, gWb, 1);
    k_bprime<<<4, 128, 0, stream>>>(gP, gMean, gScale, gamma, beta, gBp);
    k_apply<<<dim3(288, 4), 256, 0, stream>>>(x, gWb, gamma, gBp, out);
}